// Round 14
// baseline (882.611 us; speedup 1.0000x reference)
//
#include <hip/hip_runtime.h>
#include <hip/hip_bf16.h>

// Chamfer distance, B=16, N=M=4096, D=3, fp32 — R10 skeleton, 4-MFMA burst.
//
// d2 via ONE K=16 bf16 mfma_f32_32x32x16 per 32x32 tile, hi/lo bf16 split
// (slot layout verified absmax==0 in R4..R13):
//   A: [xh yh zh xh yh zh xl yl | zl fh fl 1 1 0 0 0]           (query s)
//   B: [-2xh -2yh -2zh -2xl -2yl -2zl -2xh -2yh | -2zh 1 1 fh fl 0 0 0] (t)
// Grid: dir(2) x batch(16) x strip(16 of 256 rows) = 512 blocks x 256 thr.
// g=2 row-groups/wave; CHUNKC=1024 dbuf LDS (64 KB, 2 blocks/CU); in-kernel
// B conversion (R13 proved hoisting it is a net loss). Inner loop change vs
// R10: even/odd register sets (no copy rotation) and ALL 4 MFMAs issued
// back-to-back before the 32-min3 fold -> MFMA->readback distance >= 3
// MFMAs (~24+ cyc) instead of 1. Row-mins FINAL per block -> one atomicAdd.
// 2 dispatches (4B memset + kernel).

#define BATCH   16
#define NPTS    4096
#define CHUNKC  1024
#define NCHUNKS (NPTS / CHUNKC)        // 4
#define NSTRIPS 16                     // 4096 / 256 rows per block
#define NSTEP   (CHUNKC / 64)          // 16

typedef __attribute__((ext_vector_type(8)))  short short8;
typedef __attribute__((ext_vector_type(16))) float float16;

union U4S8 { uint4 u; short8 s; };

__device__ inline unsigned int bfb(float v) {
    __hip_bfloat16 h = __float2bfloat16(v);
    unsigned short u; __builtin_memcpy(&u, &h, 2);
    return (unsigned int)u;
}
__device__ inline float bff(float v) { return __bfloat162float(__float2bfloat16(v)); }

#define ONEB 0x3F80u

__device__ inline void buildA(float x, float y, float z, uint4& w0, uint4& w1) {
    float xhf = bff(x), yhf = bff(y), zhf = bff(z);
    float f = fmaf(x, x, fmaf(y, y, z * z));
    float fhf = bff(f);
    unsigned xh = bfb(xhf), yh = bfb(yhf), zh = bfb(zhf);
    unsigned xl = bfb(x - xhf), yl = bfb(y - yhf), zl = bfb(z - zhf);
    unsigned fh = bfb(fhf), fl = bfb(f - fhf);
    w0 = make_uint4(xh | (yh << 16), zh | (xh << 16),
                    yh | (zh << 16), xl | (yl << 16));
    w1 = make_uint4(zl | (fh << 16), fl | (ONEB << 16), ONEB, 0u);
}

__device__ inline void buildB(float x, float y, float z, uint4& w0, uint4& w1) {
    float xhf = bff(x), yhf = bff(y), zhf = bff(z);
    float f = fmaf(x, x, fmaf(y, y, z * z));
    float fhf = bff(f);
    unsigned a = bfb(-2.0f * xhf), b = bfb(-2.0f * yhf), c = bfb(-2.0f * zhf);
    unsigned d = bfb(-2.0f * (x - xhf)), e = bfb(-2.0f * (y - yhf)),
             g = bfb(-2.0f * (z - zhf));
    unsigned fh = bfb(fhf), fl = bfb(f - fhf);
    w0 = make_uint4(a | (b << 16), c | (d << 16),
                    e | (g << 16), a | (b << 16));
    w1 = make_uint4(c | (ONEB << 16), ONEB | (fh << 16), fl, 0u);
}

__global__ __launch_bounds__(256, 2) void chamfer_kernel(
    const float* __restrict__ src, const float* __restrict__ tgt,
    float* __restrict__ out)
{
    __shared__ uint4 sbuf[2][2][CHUNKC];    // [buf][half][pt] = 64 KB
    __shared__ float wsum[4];

    int blk = blockIdx.x;
    const int strip = blk & (NSTRIPS - 1); blk >>= 4;
    const int b     = blk & 15;            blk >>= 4;
    const int dir   = blk;

    const int t    = threadIdx.x;
    const int lane = t & 63;
    const int w    = t >> 6;
    const int half = lane >> 5;
    const int l5   = lane & 31;

    const float* Araw = (dir ? tgt : src) + (size_t)b * NPTS * 3;  // queries
    const float* Braw = (dir ? src : tgt) + (size_t)b * NPTS * 3;  // targets

    // A fragments: 2 row-groups of 32 rows per wave (256 rows per block).
    short8 afr[2];
#pragma unroll
    for (int g = 0; g < 2; g++) {
        int row = strip * 256 + g * 128 + w * 32 + l5;
        uint4 w0, w1;
        buildA(Araw[3 * row], Araw[3 * row + 1], Araw[3 * row + 2], w0, w1);
        U4S8 tt; tt.u = half ? w1 : w0;
        afr[g] = tt.s;
    }

    // Pipelined B staging: raw loads (regs) early, convert + ds_write late.
    float nx[4][3];
    auto loadRaw = [&](int c) {
#pragma unroll
        for (int k = 0; k < 4; k++) {
            int p = c * CHUNKC + t + k * 256;
            nx[k][0] = Braw[3 * p + 0];
            nx[k][1] = Braw[3 * p + 1];
            nx[k][2] = Braw[3 * p + 2];
        }
    };
    auto convertWrite = [&](int bi) {
#pragma unroll
        for (int k = 0; k < 4; k++) {
            int lp = t + k * 256;
            uint4 w0, w1;
            buildB(nx[k][0], nx[k][1], nx[k][2], w0, w1);
            sbuf[bi][0][lp] = w0;
            sbuf[bi][1][lp] = w1;
        }
    };

    const float16 z16 = {0.f,0.f,0.f,0.f,0.f,0.f,0.f,0.f,
                         0.f,0.f,0.f,0.f,0.f,0.f,0.f,0.f};
    float rm[2][16];
#pragma unroll
    for (int g = 0; g < 2; g++)
#pragma unroll
        for (int r = 0; r < 16; r++) rm[g][r] = 1e30f;

    loadRaw(0);
    convertWrite(0);
    for (int c = 0; c < NCHUNKS; c++) {
        __syncthreads();              // buf[c&1] written; prior-iter reads done
        if (c + 1 < NCHUNKS) loadRaw(c + 1);   // issue, don't wait
        const int bi = c & 1;

        // Even/odd register sets (no copy rotation); 4 MFMAs back-to-back
        // then the 32-min3 fold (max producer->readback distance).
        U4S8 e0, e1, o0, o1;
        e0.u = sbuf[bi][half][l5];
        e1.u = sbuf[bi][half][32 + l5];
#pragma unroll
        for (int j2 = 0; j2 < NSTEP; j2 += 2) {
            // prefetch odd step while even step computes
            o0.u = sbuf[bi][half][(j2 + 1) * 64 + l5];
            o1.u = sbuf[bi][half][(j2 + 1) * 64 + 32 + l5];
            {
                float16 a00 = __builtin_amdgcn_mfma_f32_32x32x16_bf16(afr[0], e0.s, z16, 0, 0, 0);
                float16 a01 = __builtin_amdgcn_mfma_f32_32x32x16_bf16(afr[0], e1.s, z16, 0, 0, 0);
                float16 a10 = __builtin_amdgcn_mfma_f32_32x32x16_bf16(afr[1], e0.s, z16, 0, 0, 0);
                float16 a11 = __builtin_amdgcn_mfma_f32_32x32x16_bf16(afr[1], e1.s, z16, 0, 0, 0);
#pragma unroll
                for (int r = 0; r < 16; r++) {
                    rm[0][r] = fminf(fminf(a00[r], a01[r]), rm[0][r]);   // v_min3
                    rm[1][r] = fminf(fminf(a10[r], a11[r]), rm[1][r]);
                }
            }
            // prefetch next even step while odd step computes
            if (j2 + 2 < NSTEP) {
                e0.u = sbuf[bi][half][(j2 + 2) * 64 + l5];
                e1.u = sbuf[bi][half][(j2 + 2) * 64 + 32 + l5];
            }
            {
                float16 a00 = __builtin_amdgcn_mfma_f32_32x32x16_bf16(afr[0], o0.s, z16, 0, 0, 0);
                float16 a01 = __builtin_amdgcn_mfma_f32_32x32x16_bf16(afr[0], o1.s, z16, 0, 0, 0);
                float16 a10 = __builtin_amdgcn_mfma_f32_32x32x16_bf16(afr[1], o0.s, z16, 0, 0, 0);
                float16 a11 = __builtin_amdgcn_mfma_f32_32x32x16_bf16(afr[1], o1.s, z16, 0, 0, 0);
#pragma unroll
                for (int r = 0; r < 16; r++) {
                    rm[0][r] = fminf(fminf(a00[r], a01[r]), rm[0][r]);
                    rm[1][r] = fminf(fminf(a10[r], a11[r]), rm[1][r]);
                }
            }
        }
        if (c + 1 < NCHUNKS) convertWrite((c + 1) & 1);      // vmcnt hidden
    }

    // Col-fold within half (masks 1..16 over lane&31); each lane then holds
    // 2x16 final rows for its half; shfl 32 merges the halves' sums.
#pragma unroll
    for (int mask = 1; mask <= 16; mask <<= 1)
#pragma unroll
        for (int g = 0; g < 2; g++)
#pragma unroll
            for (int r = 0; r < 16; r++)
                rm[g][r] = fminf(rm[g][r], __shfl_xor(rm[g][r], mask, 64));

    float s = 0.0f;
#pragma unroll
    for (int g = 0; g < 2; g++)
#pragma unroll
        for (int r = 0; r < 16; r++) s += fmaxf(rm[g][r], 0.0f);
    s += __shfl_xor(s, 32, 64);

    if (lane == 0) wsum[w] = s;
    __syncthreads();
    if (t == 0)
        atomicAdd(out, (wsum[0] + wsum[1] + wsum[2] + wsum[3]) * (1.0f / (float)NPTS));
}

extern "C" void kernel_launch(void* const* d_in, const int* in_sizes, int n_in,
                              void* d_out, int out_size, void* d_ws, size_t ws_size,
                              hipStream_t stream)
{
    const float* src = (const float*)d_in[0];
    const float* tgt = (const float*)d_in[1];
    float* out = (float*)d_out;

    hipMemsetAsync(out, 0, sizeof(float), stream);
    chamfer_kernel<<<2 * BATCH * NSTRIPS, 256, 0, stream>>>(src, tgt, out);
}

// Round 15
// 79.483 us; speedup vs baseline: 11.1045x; 11.1045x over previous
//
#include <hip/hip_runtime.h>
#include <hip/hip_bf16.h>

// Chamfer distance, B=16, N=M=4096, D=3, fp32 — R10 + wave-staggered steps.
//
// d2 via ONE K=16 bf16 mfma_f32_32x32x16 per 32x32 tile, hi/lo bf16 split
// (slot layout verified absmax==0 in R4..R14):
//   A: [xh yh zh xh yh zh xl yl | zl fh fl 1 1 0 0 0]           (query s)
//   B: [-2xh -2yh -2zh -2xl -2yl -2zl -2xh -2yh | -2zh 1 1 fh fl 0 0 0] (t)
// Grid: dir(2) x batch(16) x strip(16 of 256 rows) = 512 blocks x 256 thr.
// g=2 row-groups/wave; CHUNKC=1024 dbuf LDS (64 KB, 2 blocks/CU); in-kernel
// B conversion; R10's rotation-prefetch inner loop UNCHANGED except each
// wave starts its 16-step walk at offset w*4 (min is order-invariant) —
// de-phases the waves so MFMA bursts of one wave overlap min3 bursts of
// another instead of colliding on the same pipe. Row-mins FINAL per block
// -> one atomicAdd. 2 dispatches (4B memset + kernel).

#define BATCH   16
#define NPTS    4096
#define CHUNKC  1024
#define NCHUNKS (NPTS / CHUNKC)        // 4
#define NSTRIPS 16                     // 4096 / 256 rows per block
#define NSTEP   (CHUNKC / 64)          // 16

typedef __attribute__((ext_vector_type(8)))  short short8;
typedef __attribute__((ext_vector_type(16))) float float16;

union U4S8 { uint4 u; short8 s; };

__device__ inline unsigned int bfb(float v) {
    __hip_bfloat16 h = __float2bfloat16(v);
    unsigned short u; __builtin_memcpy(&u, &h, 2);
    return (unsigned int)u;
}
__device__ inline float bff(float v) { return __bfloat162float(__float2bfloat16(v)); }

#define ONEB 0x3F80u

__device__ inline void buildA(float x, float y, float z, uint4& w0, uint4& w1) {
    float xhf = bff(x), yhf = bff(y), zhf = bff(z);
    float f = fmaf(x, x, fmaf(y, y, z * z));
    float fhf = bff(f);
    unsigned xh = bfb(xhf), yh = bfb(yhf), zh = bfb(zhf);
    unsigned xl = bfb(x - xhf), yl = bfb(y - yhf), zl = bfb(z - zhf);
    unsigned fh = bfb(fhf), fl = bfb(f - fhf);
    w0 = make_uint4(xh | (yh << 16), zh | (xh << 16),
                    yh | (zh << 16), xl | (yl << 16));
    w1 = make_uint4(zl | (fh << 16), fl | (ONEB << 16), ONEB, 0u);
}

__device__ inline void buildB(float x, float y, float z, uint4& w0, uint4& w1) {
    float xhf = bff(x), yhf = bff(y), zhf = bff(z);
    float f = fmaf(x, x, fmaf(y, y, z * z));
    float fhf = bff(f);
    unsigned a = bfb(-2.0f * xhf), b = bfb(-2.0f * yhf), c = bfb(-2.0f * zhf);
    unsigned d = bfb(-2.0f * (x - xhf)), e = bfb(-2.0f * (y - yhf)),
             g = bfb(-2.0f * (z - zhf));
    unsigned fh = bfb(fhf), fl = bfb(f - fhf);
    w0 = make_uint4(a | (b << 16), c | (d << 16),
                    e | (g << 16), a | (b << 16));
    w1 = make_uint4(c | (ONEB << 16), ONEB | (fh << 16), fl, 0u);
}

__global__ __launch_bounds__(256, 2) void chamfer_kernel(
    const float* __restrict__ src, const float* __restrict__ tgt,
    float* __restrict__ out)
{
    __shared__ uint4 sbuf[2][2][CHUNKC];    // [buf][half][pt] = 64 KB
    __shared__ float wsum[4];

    int blk = blockIdx.x;
    const int strip = blk & (NSTRIPS - 1); blk >>= 4;
    const int b     = blk & 15;            blk >>= 4;
    const int dir   = blk;

    const int t    = threadIdx.x;
    const int lane = t & 63;
    const int w    = t >> 6;
    const int half = lane >> 5;
    const int l5   = lane & 31;
    const int start = w * 4;               // wave-staggered step origin

    const float* Araw = (dir ? tgt : src) + (size_t)b * NPTS * 3;  // queries
    const float* Braw = (dir ? src : tgt) + (size_t)b * NPTS * 3;  // targets

    // A fragments: 2 row-groups of 32 rows per wave (256 rows per block).
    short8 afr[2];
#pragma unroll
    for (int g = 0; g < 2; g++) {
        int row = strip * 256 + g * 128 + w * 32 + l5;
        uint4 w0, w1;
        buildA(Araw[3 * row], Araw[3 * row + 1], Araw[3 * row + 2], w0, w1);
        U4S8 tt; tt.u = half ? w1 : w0;
        afr[g] = tt.s;
    }

    // Pipelined B staging: raw loads (regs) early, convert + ds_write late.
    float nx[4][3];
    auto loadRaw = [&](int c) {
#pragma unroll
        for (int k = 0; k < 4; k++) {
            int p = c * CHUNKC + t + k * 256;
            nx[k][0] = Braw[3 * p + 0];
            nx[k][1] = Braw[3 * p + 1];
            nx[k][2] = Braw[3 * p + 2];
        }
    };
    auto convertWrite = [&](int bi) {
#pragma unroll
        for (int k = 0; k < 4; k++) {
            int lp = t + k * 256;
            uint4 w0, w1;
            buildB(nx[k][0], nx[k][1], nx[k][2], w0, w1);
            sbuf[bi][0][lp] = w0;
            sbuf[bi][1][lp] = w1;
        }
    };

    const float16 z16 = {0.f,0.f,0.f,0.f,0.f,0.f,0.f,0.f,
                         0.f,0.f,0.f,0.f,0.f,0.f,0.f,0.f};
    float rm[2][16];
#pragma unroll
    for (int g = 0; g < 2; g++)
#pragma unroll
        for (int r = 0; r < 16; r++) rm[g][r] = 1e30f;

    loadRaw(0);
    convertWrite(0);
    for (int c = 0; c < NCHUNKS; c++) {
        __syncthreads();              // buf[c&1] written; prior-iter reads done
        if (c + 1 < NCHUNKS) loadRaw(c + 1);   // issue, don't wait
        const int bi = c & 1;

        // R10's software-pipelined MFMA loop, wave-staggered: wave w visits
        // steps (start + j2) & 15 — order is irrelevant for min-folding.
        U4S8 c0, c1, n0, n1;
        c0.u = sbuf[bi][half][start * 64 + l5];
        c1.u = sbuf[bi][half][start * 64 + 32 + l5];
#pragma unroll 4
        for (int j2 = 0; j2 < NSTEP; j2++) {
            int nj = (start + j2 + 1) & (NSTEP - 1);   // wrap: harmless re-read
            n0.u = sbuf[bi][half][nj * 64 + l5];
            n1.u = sbuf[bi][half][nj * 64 + 32 + l5];
#pragma unroll
            for (int g = 0; g < 2; g++) {
                float16 a0 = __builtin_amdgcn_mfma_f32_32x32x16_bf16(afr[g], c0.s, z16, 0, 0, 0);
                float16 a1 = __builtin_amdgcn_mfma_f32_32x32x16_bf16(afr[g], c1.s, z16, 0, 0, 0);
#pragma unroll
                for (int r = 0; r < 16; r++)
                    rm[g][r] = fminf(fminf(a0[r], a1[r]), rm[g][r]);   // v_min3
            }
            c0 = n0; c1 = n1;
        }
        if (c + 1 < NCHUNKS) convertWrite((c + 1) & 1);      // vmcnt hidden
    }

    // Col-fold within half (masks 1..16 over lane&31); each lane then holds
    // 2x16 final rows for its half; shfl 32 merges the halves' sums.
#pragma unroll
    for (int mask = 1; mask <= 16; mask <<= 1)
#pragma unroll
        for (int g = 0; g < 2; g++)
#pragma unroll
            for (int r = 0; r < 16; r++)
                rm[g][r] = fminf(rm[g][r], __shfl_xor(rm[g][r], mask, 64));

    float s = 0.0f;
#pragma unroll
    for (int g = 0; g < 2; g++)
#pragma unroll
        for (int r = 0; r < 16; r++) s += fmaxf(rm[g][r], 0.0f);
    s += __shfl_xor(s, 32, 64);

    if (lane == 0) wsum[w] = s;
    __syncthreads();
    if (t == 0)
        atomicAdd(out, (wsum[0] + wsum[1] + wsum[2] + wsum[3]) * (1.0f / (float)NPTS));
}

extern "C" void kernel_launch(void* const* d_in, const int* in_sizes, int n_in,
                              void* d_out, int out_size, void* d_ws, size_t ws_size,
                              hipStream_t stream)
{
    const float* src = (const float*)d_in[0];
    const float* tgt = (const float*)d_in[1];
    float* out = (float*)d_out;

    hipMemsetAsync(out, 0, sizeof(float), stream);
    chamfer_kernel<<<2 * BATCH * NSTRIPS, 256, 0, stream>>>(src, tgt, out);
}